// Round 5
// baseline (290.794 us; speedup 1.0000x reference)
//
#include <hip/hip_runtime.h>
#include <hip/hip_bf16.h>
#include <stdint.h>

typedef __attribute__((ext_vector_type(8))) __bf16 bf16x8;
typedef __attribute__((ext_vector_type(4))) float f32x4;
typedef __attribute__((ext_vector_type(4))) unsigned int u32x4;

#define BM 256
#define BN 256
#define BKT 32            // K per ring slot
#define RING 4            // prefetch depth 3
#define SLOT_BYTES 16384  // 256 rows x 32 cols x 2B

// ---------------- NVFP4 quantize-dequantize (factored: no global scale) ----------------

__device__ __forceinline__ float fp8_e4m3_rne(float x) {
  if (x < 0.015625f) {                       // below min normal 2^-6: subnormal grid 2^-9
    return rintf(x * 512.0f) * 0.001953125f;
  }
  uint32_t u = __float_as_uint(x);
  uint32_t keep = u & 0xFFF00000u;
  uint32_t rem  = u & 0x000FFFFFu;
  uint32_t lsb  = (u >> 20) & 1u;
  if (rem > 0x80000u || (rem == 0x80000u && lsb)) keep += 0x100000u;
  return __uint_as_float(keep);
}

__device__ __forceinline__ float snap_lvl(float a) {
  if (a > 5.0f)  return 6.0f;
  if (a > 3.5f)  return 4.0f;
  if (a > 2.5f)  return 3.0f;
  if (a > 1.75f) return 2.0f;
  if (a > 1.25f) return 1.5f;
  if (a > 0.75f) return 1.0f;
  if (a > 0.25f) return 0.5f;
  return 0.0f;
}

__global__ __launch_bounds__(256) void quant_nvfp4(
    const float* __restrict__ in, unsigned short* __restrict__ out,
    const float* __restrict__ gsp, int nblk) {
  int b = blockIdx.x * 256 + threadIdx.x;
  if (b >= nblk) return;
  float gs = gsp[0];
  const float4* p = reinterpret_cast<const float4*>(in) + (size_t)b * 4;
  float v[16];
#pragma unroll
  for (int i = 0; i < 4; ++i) {
    float4 t4 = p[i];
    v[i * 4 + 0] = t4.x; v[i * 4 + 1] = t4.y;
    v[i * 4 + 2] = t4.z; v[i * 4 + 3] = t4.w;
  }
  float amax = 0.0f;
#pragma unroll
  for (int i = 0; i < 16; ++i) amax = fmaxf(amax, fabsf(v[i]));
  float bs8 = fp8_e4m3_rne(amax / (6.0f * gs));
  float scale = fmaxf(bs8 * gs, 1e-12f);
  unsigned short o[16];
#pragma unroll
  for (int i = 0; i < 16; ++i) {
    float q = v[i] / scale;
    float a = fminf(fabsf(q), 6.0f);
    float val = copysignf(snap_lvl(a) * bs8, q);
    o[i] = (unsigned short)(__float_as_uint(val) >> 16);
  }
  uint4 w0 = make_uint4((uint32_t)o[0] | ((uint32_t)o[1] << 16),
                        (uint32_t)o[2] | ((uint32_t)o[3] << 16),
                        (uint32_t)o[4] | ((uint32_t)o[5] << 16),
                        (uint32_t)o[6] | ((uint32_t)o[7] << 16));
  uint4 w1 = make_uint4((uint32_t)o[8]  | ((uint32_t)o[9]  << 16),
                        (uint32_t)o[10] | ((uint32_t)o[11] << 16),
                        (uint32_t)o[12] | ((uint32_t)o[13] << 16),
                        (uint32_t)o[14] | ((uint32_t)o[15] << 16));
  uint4* op = reinterpret_cast<uint4*>(out + (size_t)b * 16);
  op[0] = w0;
  op[1] = w1;
}

// ---------------- bf16 GEMM, C = A * B^T ; 256x256 tile, ring-4 BK=32 ----------------

__device__ __forceinline__ void async_lds16(const void* g, void* l) {
  __builtin_amdgcn_global_load_lds((__attribute__((address_space(1))) void*)(g),
                                   (__attribute__((address_space(3))) void*)(l),
                                   16, 0, 0);
}

// ordered LDS vector read (volatile asm preserves mutual order -> lgkm counts exact)
#define DSR(dst, a) asm volatile("ds_read_b128 %0, %1" : "=v"(dst) : "v"(a))
#define LGKM(N) do { asm volatile("s_waitcnt lgkmcnt(" #N ")" ::: "memory"); \
                     __builtin_amdgcn_sched_barrier(0); } while (0)
#define BCB(x) __builtin_bit_cast(bf16x8, x)

#define MF4(mi, ar) do {                                                       \
    acc[mi][0] = __builtin_amdgcn_mfma_f32_16x16x32_bf16(BCB(ar), BCB(rb0), acc[mi][0], 0, 0, 0); \
    acc[mi][1] = __builtin_amdgcn_mfma_f32_16x16x32_bf16(BCB(ar), BCB(rb1), acc[mi][1], 0, 0, 0); \
    acc[mi][2] = __builtin_amdgcn_mfma_f32_16x16x32_bf16(BCB(ar), BCB(rb2), acc[mi][2], 0, 0, 0); \
    acc[mi][3] = __builtin_amdgcn_mfma_f32_16x16x32_bf16(BCB(ar), BCB(rb3), acc[mi][3], 0, 0, 0); \
  } while (0)

// one K32 tile: single vmcnt+barrier, stage T+3 early, 12 ds_reads threaded
// inside one continuous 32-MFMA stream via exact counted lgkm.
#define TILE(T, DO_STAGE, VMWAIT) do {                                         \
    const unsigned soff = (unsigned)(((T) & 3) * SLOT_BYTES);                  \
    VMWAIT;                                                                    \
    __builtin_amdgcn_s_barrier();                                              \
    if (DO_STAGE) {                                                            \
      char* _la = (char*)As + (((T) + 3) & 3) * SLOT_BYTES;                    \
      char* _lb = (char*)Bs + (((T) + 3) & 3) * SLOT_BYTES;                    \
      async_lds16(pA0 + (size_t)((T) + 3) * BKT, _la + lo0);                   \
      async_lds16(pB0 + (size_t)((T) + 3) * BKT, _lb + lo0);                   \
      async_lds16(pA1 + (size_t)((T) + 3) * BKT, _la + lo1);                   \
      async_lds16(pB1 + (size_t)((T) + 3) * BKT, _lb + lo1);                   \
    }                                                                          \
    u32x4 rb0, rb1, rb2, rb3, ra0, ra1, ra2, ra3, ra4, ra5, ra6, ra7;          \
    DSR(rb0, adB[0] + soff); DSR(rb1, adB[1] + soff);                          \
    DSR(rb2, adB[2] + soff); DSR(rb3, adB[3] + soff);                          \
    DSR(ra0, adA[0] + soff); DSR(ra1, adA[1] + soff);                          \
    DSR(ra2, adA[2] + soff); DSR(ra3, adA[3] + soff);                          \
    __builtin_amdgcn_sched_barrier(0);                                         \
    LGKM(3); __builtin_amdgcn_s_setprio(1); MF4(0, ra0);                       \
    LGKM(2); MF4(1, ra1);                                                      \
    __builtin_amdgcn_sched_barrier(0);                                         \
    DSR(ra4, adA[4] + soff); DSR(ra5, adA[5] + soff);                          \
    DSR(ra6, adA[6] + soff); DSR(ra7, adA[7] + soff);                          \
    __builtin_amdgcn_sched_barrier(0);                                         \
    LGKM(5); MF4(2, ra2);                                                      \
    LGKM(4); MF4(3, ra3);                                                      \
    LGKM(3); MF4(4, ra4);                                                      \
    LGKM(2); MF4(5, ra5);                                                      \
    LGKM(1); MF4(6, ra6);                                                      \
    LGKM(0); MF4(7, ra7);                                                      \
    __builtin_amdgcn_s_setprio(0);                                             \
    __builtin_amdgcn_sched_barrier(0);                                         \
  } while (0)

#define STAGE_TILE(s) {                                                        \
    char* _la = (char*)As + ((s) & 3) * SLOT_BYTES;                            \
    char* _lb = (char*)Bs + ((s) & 3) * SLOT_BYTES;                            \
    async_lds16(pA0 + (size_t)(s) * BKT, _la + lo0);                           \
    async_lds16(pB0 + (size_t)(s) * BKT, _lb + lo0);                           \
    async_lds16(pA1 + (size_t)(s) * BKT, _la + lo1);                           \
    async_lds16(pB1 + (size_t)(s) * BKT, _lb + lo1);                           \
  }

__global__ __launch_bounds__(512, 2) void gemm_bt_bf16(
    const unsigned short* __restrict__ A, const unsigned short* __restrict__ B,
    const float* __restrict__ bias, const float* __restrict__ gsx,
    const float* __restrict__ gsw, float* __restrict__ C,
    int M, int N, int K) {
  __shared__ __align__(16) unsigned short As[RING * 8192];
  __shared__ __align__(16) unsigned short Bs[RING * 8192];

  const int t = threadIdx.x;
  const int l = t & 63;
  const int w = t >> 6;
  const int wm = w >> 2, wn = w & 3;     // 2x4 waves; wave tile = 128(M) x 64(N)

  // bijective XCD swizzle (nwg = 512, divisible by 8)
  const int nbn = N / BN;
  const int nwg = (M / BM) * nbn;
  const int cpx = nwg >> 3;
  int bid = blockIdx.x;
  int logical = (bid & 7) * cpx + (bid >> 3);
  const int bm = logical / nbn, bn = logical % nbn;
  const int brow = bm * BM, bcol = bn * BN;

  // staging: linear LDS dest, inverse-swizzled global source (involution q^(((q>>7)&3)<<4))
  unsigned int b0 = (unsigned int)t * 16u;
  unsigned int b1 = b0 + 8192u;
  unsigned int bp0 = b0 ^ (((b0 >> 7) & 3u) << 4);
  unsigned int bp1 = b1 ^ (((b1 >> 7) & 3u) << 4);
  const unsigned int lo0 = b0, lo1 = b1;
  const unsigned short* pA0 = A + (size_t)(brow + (bp0 >> 6)) * K + ((bp0 & 63u) >> 1);
  const unsigned short* pA1 = A + (size_t)(brow + (bp1 >> 6)) * K + ((bp1 & 63u) >> 1);
  const unsigned short* pB0 = B + (size_t)(bcol + (bp0 >> 6)) * K + ((bp0 & 63u) >> 1);
  const unsigned short* pB1 = B + (size_t)(bcol + (bp1 >> 6)) * K + ((bp1 & 63u) >> 1);

  // swizzled fragment read addresses (32-bit LDS offsets)
  const unsigned baseAu = (unsigned)(uintptr_t)(&As[0]);
  const unsigned baseBu = (unsigned)(uintptr_t)(&Bs[0]);
  unsigned int adA[8], adB[4];
#pragma unroll
  for (int mi = 0; mi < 8; ++mi) {
    unsigned int r = wm * 128 + mi * 16 + (l & 15);
    unsigned int q = r * 64 + ((l >> 4) << 4);
    adA[mi] = baseAu + (q ^ (((q >> 7) & 3u) << 4));
  }
#pragma unroll
  for (int ni = 0; ni < 4; ++ni) {
    unsigned int r = wn * 64 + ni * 16 + (l & 15);
    unsigned int q = r * 64 + ((l >> 4) << 4);
    adB[ni] = baseBu + (q ^ (((q >> 7) & 3u) << 4));
  }

  f32x4 acc[8][4] = {};

  const int nsub = K / BKT;   // 128

  // prologue: stage tiles 0..2 (12 loads in flight; tile 0's vmcnt(8) confirms stage 0)
  STAGE_TILE(0);
  STAGE_TILE(1);
  STAGE_TILE(2);

#pragma unroll 1
  for (int T = 0; T < nsub - 3; ++T) {
    TILE(T, 1, asm volatile("s_waitcnt vmcnt(8)" ::: "memory"));
  }
  TILE(nsub - 3, 0, asm volatile("s_waitcnt vmcnt(8)" ::: "memory"));
  TILE(nsub - 2, 0, asm volatile("s_waitcnt vmcnt(4)" ::: "memory"));
  TILE(nsub - 1, 0, asm volatile("s_waitcnt vmcnt(0)" ::: "memory"));

  // ---- epilogue ----
  const float gscale = gsx[0] * gsw[0];
  float bias_r[4];
#pragma unroll
  for (int ni = 0; ni < 4; ++ni)
    bias_r[ni] = bias[bcol + wn * 64 + ni * 16 + (l & 15)];
#pragma unroll
  for (int mi = 0; mi < 8; ++mi) {
#pragma unroll
    for (int ni = 0; ni < 4; ++ni) {
#pragma unroll
      for (int r = 0; r < 4; ++r) {
        int row = brow + wm * 128 + mi * 16 + (l >> 4) * 4 + r;
        int col = bcol + wn * 64 + ni * 16 + (l & 15);
        C[(size_t)row * N + col] = acc[mi][ni][r] * gscale + bias_r[ni];
      }
    }
  }
}

// ---------------- launch ----------------

extern "C" void kernel_launch(void* const* d_in, const int* in_sizes, int n_in,
                              void* d_out, int out_size, void* d_ws, size_t ws_size,
                              hipStream_t stream) {
  const float* x    = (const float*)d_in[0];
  const float* wgt  = (const float*)d_in[1];
  const float* bias = (const float*)d_in[2];
  const float* isc  = (const float*)d_in[3];
  const float* wsc  = (const float*)d_in[4];
  float* out = (float*)d_out;

  const int N = in_sizes[2];            // 4096
  const int K = in_sizes[1] / N;        // 4096
  const int M = in_sizes[0] / K;        // 8192

  unsigned short* Aq = (unsigned short*)d_ws;
  unsigned short* Bq = Aq + (size_t)M * K;

  int nblkA = M * K / 16;
  quant_nvfp4<<<(nblkA + 255) / 256, 256, 0, stream>>>(x, Aq, isc, nblkA);
  int nblkB = N * K / 16;
  quant_nvfp4<<<(nblkB + 255) / 256, 256, 0, stream>>>(wgt, Bq, wsc, nblkB);

  dim3 grid((M / BM) * (N / BN));
  gemm_bt_bf16<<<grid, 512, 0, stream>>>(Aq, Bq, bias, isc, wsc, out, M, N, K);
}

// Round 6
// 282.138 us; speedup vs baseline: 1.0307x; 1.0307x over previous
//
#include <hip/hip_runtime.h>
#include <hip/hip_bf16.h>
#include <stdint.h>

typedef __attribute__((ext_vector_type(8))) __bf16 bf16x8;
typedef __attribute__((ext_vector_type(4))) float f32x4;
typedef __attribute__((ext_vector_type(4))) unsigned int u32x4;

#define BM 256
#define BN 256
#define BKT 32              // K per ring slot
#define SLOT 16384          // 256 rows x 32 cols x 2B
// ring-5: slots for tiles T..T+4 ; LDS = 5*(16K+16K) = 160 KiB (CU max)

// ---------------- NVFP4 quantize-dequantize (factored: no global scale) ----------------

__device__ __forceinline__ float fp8_e4m3_rne(float x) {
  if (x < 0.015625f) {                       // below min normal 2^-6: subnormal grid 2^-9
    return rintf(x * 512.0f) * 0.001953125f;
  }
  uint32_t u = __float_as_uint(x);
  uint32_t keep = u & 0xFFF00000u;
  uint32_t rem  = u & 0x000FFFFFu;
  uint32_t lsb  = (u >> 20) & 1u;
  if (rem > 0x80000u || (rem == 0x80000u && lsb)) keep += 0x100000u;
  return __uint_as_float(keep);
}

__device__ __forceinline__ float snap_lvl(float a) {
  if (a > 5.0f)  return 6.0f;
  if (a > 3.5f)  return 4.0f;
  if (a > 2.5f)  return 3.0f;
  if (a > 1.75f) return 2.0f;
  if (a > 1.25f) return 1.5f;
  if (a > 0.75f) return 1.0f;
  if (a > 0.25f) return 0.5f;
  return 0.0f;
}

__global__ __launch_bounds__(256) void quant_nvfp4(
    const float* __restrict__ in, unsigned short* __restrict__ out,
    const float* __restrict__ gsp, int nblk) {
  int b = blockIdx.x * 256 + threadIdx.x;
  if (b >= nblk) return;
  float gs = gsp[0];
  const float4* p = reinterpret_cast<const float4*>(in) + (size_t)b * 4;
  float v[16];
#pragma unroll
  for (int i = 0; i < 4; ++i) {
    float4 t4 = p[i];
    v[i * 4 + 0] = t4.x; v[i * 4 + 1] = t4.y;
    v[i * 4 + 2] = t4.z; v[i * 4 + 3] = t4.w;
  }
  float amax = 0.0f;
#pragma unroll
  for (int i = 0; i < 16; ++i) amax = fmaxf(amax, fabsf(v[i]));
  float bs8 = fp8_e4m3_rne(amax / (6.0f * gs));
  float scale = fmaxf(bs8 * gs, 1e-12f);
  unsigned short o[16];
#pragma unroll
  for (int i = 0; i < 16; ++i) {
    float q = v[i] / scale;
    float a = fminf(fabsf(q), 6.0f);
    float val = copysignf(snap_lvl(a) * bs8, q);
    o[i] = (unsigned short)(__float_as_uint(val) >> 16);
  }
  uint4 w0 = make_uint4((uint32_t)o[0] | ((uint32_t)o[1] << 16),
                        (uint32_t)o[2] | ((uint32_t)o[3] << 16),
                        (uint32_t)o[4] | ((uint32_t)o[5] << 16),
                        (uint32_t)o[6] | ((uint32_t)o[7] << 16));
  uint4 w1 = make_uint4((uint32_t)o[8]  | ((uint32_t)o[9]  << 16),
                        (uint32_t)o[10] | ((uint32_t)o[11] << 16),
                        (uint32_t)o[12] | ((uint32_t)o[13] << 16),
                        (uint32_t)o[14] | ((uint32_t)o[15] << 16));
  uint4* op = reinterpret_cast<uint4*>(out + (size_t)b * 16);
  op[0] = w0;
  op[1] = w1;
}

// ---------------- bf16 GEMM, C = A * B^T ; 256x256 tile, ring-5, 2-tile windows ----------------

__device__ __forceinline__ void async_lds16(const void* g, void* l) {
  __builtin_amdgcn_global_load_lds((__attribute__((address_space(1))) void*)(g),
                                   (__attribute__((address_space(3))) void*)(l),
                                   16, 0, 0);
}

#define DSR(dst, a) asm volatile("ds_read_b128 %0, %1" : "=v"(dst) : "v"(a))
#define LGKM(N) do { asm volatile("s_waitcnt lgkmcnt(" #N ")" ::: "memory"); \
                     __builtin_amdgcn_sched_barrier(0); } while (0)
#define BCB(x) __builtin_bit_cast(bf16x8, x)

#define MF4(mi, ar, b0, b1, b2, b3) do {                                       \
    acc[mi][0] = __builtin_amdgcn_mfma_f32_16x16x32_bf16(BCB(ar), BCB(b0), acc[mi][0], 0, 0, 0); \
    acc[mi][1] = __builtin_amdgcn_mfma_f32_16x16x32_bf16(BCB(ar), BCB(b1), acc[mi][1], 0, 0, 0); \
    acc[mi][2] = __builtin_amdgcn_mfma_f32_16x16x32_bf16(BCB(ar), BCB(b2), acc[mi][2], 0, 0, 0); \
    acc[mi][3] = __builtin_amdgcn_mfma_f32_16x16x32_bf16(BCB(ar), BCB(b3), acc[mi][3], 0, 0, 0); \
  } while (0)

#define STAGE(tile, soff) {                                                    \
    char* _la = (char*)As + (soff);                                            \
    char* _lb = (char*)Bs + (soff);                                            \
    async_lds16(pA0 + (size_t)(tile) * BKT, _la + lo0);                        \
    async_lds16(pB0 + (size_t)(tile) * BKT, _lb + lo0);                        \
    async_lds16(pA1 + (size_t)(tile) * BKT, _la + lo1);                        \
    async_lds16(pB1 + (size_t)(tile) * BKT, _lb + lo1);                        \
  }

// One window = tiles {ta, ta+1} in slots oa/ob; stages ta+3 -> o3, ta+4 -> o4.
// RAW: vmcnt(VM)+barrier confirms stage(ta+1) for ALL waves.
// WAR: o3/o4 slot readers drained (final LGKM(0)) before the previous barrier.
// Tile-b reads interleaved into tile-a's MFMA chain (peak lgkm 12 <= 15).
#define WINDOW(VMSTR, ta, oa, ob, o3, o4, DO3, DO4) do {                       \
    u32x4 rb0, rb1, rb2, rb3, ra0, ra1, ra2, ra3, ra4, ra5, ra6, ra7;          \
    u32x4 qb0, qb1, qb2, qb3, qa0, qa1, qa2, qa3, qa4, qa5, qa6, qa7;          \
    asm volatile("s_waitcnt vmcnt(" VMSTR ")" ::: "memory");                   \
    __builtin_amdgcn_s_barrier();                                              \
    if (DO3) STAGE((ta) + 3, o3);                                              \
    if (DO4) STAGE((ta) + 4, o4);                                              \
    DSR(rb0, adB[0] + (oa)); DSR(rb1, adB[1] + (oa));                          \
    DSR(rb2, adB[2] + (oa)); DSR(rb3, adB[3] + (oa));                          \
    DSR(ra0, adA[0] + (oa)); DSR(ra1, adA[1] + (oa));                          \
    DSR(ra2, adA[2] + (oa)); DSR(ra3, adA[3] + (oa));                          \
    DSR(ra4, adA[4] + (oa)); DSR(ra5, adA[5] + (oa));                          \
    DSR(ra6, adA[6] + (oa)); DSR(ra7, adA[7] + (oa));                          \
    __builtin_amdgcn_sched_barrier(0);                                         \
    LGKM(7); __builtin_amdgcn_s_setprio(1); MF4(0, ra0, rb0, rb1, rb2, rb3);   \
    LGKM(6); MF4(1, ra1, rb0, rb1, rb2, rb3);                                  \
    LGKM(5); MF4(2, ra2, rb0, rb1, rb2, rb3);                                  \
    LGKM(4); MF4(3, ra3, rb0, rb1, rb2, rb3);                                  \
    LGKM(3); MF4(4, ra4, rb0, rb1, rb2, rb3);                                  \
    DSR(qb0, adB[0] + (ob)); DSR(qb1, adB[1] + (ob));                          \
    DSR(qb2, adB[2] + (ob)); DSR(qb3, adB[3] + (ob));                          \
    DSR(qa0, adA[0] + (ob)); DSR(qa1, adA[1] + (ob));                          \
    DSR(qa2, adA[2] + (ob)); DSR(qa3, adA[3] + (ob));                          \
    __builtin_amdgcn_sched_barrier(0);                                         \
    LGKM(10); MF4(5, ra5, rb0, rb1, rb2, rb3);                                 \
    LGKM(9);  MF4(6, ra6, rb0, rb1, rb2, rb3);                                 \
    LGKM(8);  MF4(7, ra7, rb0, rb1, rb2, rb3);                                 \
    DSR(qa4, adA[4] + (ob)); DSR(qa5, adA[5] + (ob));                          \
    DSR(qa6, adA[6] + (ob)); DSR(qa7, adA[7] + (ob));                          \
    __builtin_amdgcn_sched_barrier(0);                                         \
    LGKM(7); MF4(0, qa0, qb0, qb1, qb2, qb3);                                  \
    LGKM(6); MF4(1, qa1, qb0, qb1, qb2, qb3);                                  \
    LGKM(5); MF4(2, qa2, qb0, qb1, qb2, qb3);                                  \
    LGKM(4); MF4(3, qa3, qb0, qb1, qb2, qb3);                                  \
    LGKM(3); MF4(4, qa4, qb0, qb1, qb2, qb3);                                  \
    LGKM(2); MF4(5, qa5, qb0, qb1, qb2, qb3);                                  \
    LGKM(1); MF4(6, qa6, qb0, qb1, qb2, qb3);                                  \
    LGKM(0); MF4(7, qa7, qb0, qb1, qb2, qb3);                                  \
    __builtin_amdgcn_s_setprio(0);                                             \
    __builtin_amdgcn_sched_barrier(0);                                         \
  } while (0)

__global__ __launch_bounds__(512, 2) void gemm_bt_bf16(
    const unsigned short* __restrict__ A, const unsigned short* __restrict__ B,
    const float* __restrict__ bias, const float* __restrict__ gsx,
    const float* __restrict__ gsw, float* __restrict__ C,
    int M, int N, int K) {
  __shared__ __align__(16) unsigned short As[5 * 8192];   // 80 KiB
  __shared__ __align__(16) unsigned short Bs[5 * 8192];   // 80 KiB

  const int t = threadIdx.x;
  const int l = t & 63;
  const int w = t >> 6;
  const int wm = w >> 2, wn = w & 3;     // 2x4 waves; wave tile = 128(M) x 64(N)

  // bijective XCD swizzle (nwg = 512, divisible by 8)
  const int nbn = N / BN;
  const int nwg = (M / BM) * nbn;
  const int cpx = nwg >> 3;
  int bid = blockIdx.x;
  int logical = (bid & 7) * cpx + (bid >> 3);
  const int bm = logical / nbn, bn = logical % nbn;
  const int brow = bm * BM, bcol = bn * BN;

  // staging: linear LDS dest, inverse-swizzled global source (involution q^(((q>>7)&3)<<4))
  unsigned int b0 = (unsigned int)t * 16u;
  unsigned int b1 = b0 + 8192u;
  unsigned int bp0 = b0 ^ (((b0 >> 7) & 3u) << 4);
  unsigned int bp1 = b1 ^ (((b1 >> 7) & 3u) << 4);
  const unsigned int lo0 = b0, lo1 = b1;
  const unsigned short* pA0 = A + (size_t)(brow + (bp0 >> 6)) * K + ((bp0 & 63u) >> 1);
  const unsigned short* pA1 = A + (size_t)(brow + (bp1 >> 6)) * K + ((bp1 & 63u) >> 1);
  const unsigned short* pB0 = B + (size_t)(bcol + (bp0 >> 6)) * K + ((bp0 & 63u) >> 1);
  const unsigned short* pB1 = B + (size_t)(bcol + (bp1 >> 6)) * K + ((bp1 & 63u) >> 1);

  // swizzled fragment read addresses (32-bit LDS offsets)
  const unsigned baseAu = (unsigned)(uintptr_t)(&As[0]);
  const unsigned baseBu = (unsigned)(uintptr_t)(&Bs[0]);
  unsigned int adA[8], adB[4];
#pragma unroll
  for (int mi = 0; mi < 8; ++mi) {
    unsigned int r = wm * 128 + mi * 16 + (l & 15);
    unsigned int q = r * 64 + ((l >> 4) << 4);
    adA[mi] = baseAu + (q ^ (((q >> 7) & 3u) << 4));
  }
#pragma unroll
  for (int ni = 0; ni < 4; ++ni) {
    unsigned int r = wn * 64 + ni * 16 + (l & 15);
    unsigned int q = r * 64 + ((l >> 4) << 4);
    adB[ni] = baseBu + (q ^ (((q >> 7) & 3u) << 4));
  }

  f32x4 acc[8][4] = {};

  // prologue: stage tiles 0,1,2 into slots 0,1,2 (12 loads in flight)
  STAGE(0, 0);
  STAGE(1, SLOT);
  STAGE(2, 2 * SLOT);

  // steady state: 62 full windows (tiles 0..123, stages 3..126)
  int sa = 0;
#pragma unroll 1
  for (int k = 0; k < 62; ++k) {
    int ta = 2 * k;
    int sb = sa + 1; if (sb >= 5) sb -= 5;
    int s3 = sa + 3; if (s3 >= 5) s3 -= 5;
    int s4 = sa + 4; if (s4 >= 5) s4 -= 5;
    WINDOW("4", ta, sa * SLOT, sb * SLOT, s3 * SLOT, s4 * SLOT, 1, 1);
    sa += 2; if (sa >= 5) sa -= 5;
  }
  // tail: tiles 124,125 (slots 4,0), stage tile 127 -> slot 2
  WINDOW("4", 124, 4 * SLOT, 0 * SLOT, 2 * SLOT, 0, 1, 0);
  // tail: tiles 126,127 (slots 1,2), no stages, drain all
  WINDOW("0", 126, 1 * SLOT, 2 * SLOT, 0, 0, 0, 0);

  // ---- epilogue ----
  const float gscale = gsx[0] * gsw[0];
  float bias_r[4];
#pragma unroll
  for (int ni = 0; ni < 4; ++ni)
    bias_r[ni] = bias[bcol + wn * 64 + ni * 16 + (l & 15)];
#pragma unroll
  for (int mi = 0; mi < 8; ++mi) {
#pragma unroll
    for (int ni = 0; ni < 4; ++ni) {
#pragma unroll
      for (int r = 0; r < 4; ++r) {
        int row = brow + wm * 128 + mi * 16 + (l >> 4) * 4 + r;
        int col = bcol + wn * 64 + ni * 16 + (l & 15);
        C[(size_t)row * N + col] = acc[mi][ni][r] * gscale + bias_r[ni];
      }
    }
  }
}

// ---------------- launch ----------------

extern "C" void kernel_launch(void* const* d_in, const int* in_sizes, int n_in,
                              void* d_out, int out_size, void* d_ws, size_t ws_size,
                              hipStream_t stream) {
  const float* x    = (const float*)d_in[0];
  const float* wgt  = (const float*)d_in[1];
  const float* bias = (const float*)d_in[2];
  const float* isc  = (const float*)d_in[3];
  const float* wsc  = (const float*)d_in[4];
  float* out = (float*)d_out;

  const int N = in_sizes[2];            // 4096
  const int K = in_sizes[1] / N;        // 4096
  const int M = in_sizes[0] / K;        // 8192

  unsigned short* Aq = (unsigned short*)d_ws;
  unsigned short* Bq = Aq + (size_t)M * K;

  int nblkA = M * K / 16;
  quant_nvfp4<<<(nblkA + 255) / 256, 256, 0, stream>>>(x, Aq, isc, nblkA);
  int nblkB = N * K / 16;
  quant_nvfp4<<<(nblkB + 255) / 256, 256, 0, stream>>>(wgt, Bq, wsc, nblkB);

  dim3 grid((M / BM) * (N / BN));
  gemm_bt_bf16<<<grid, 512, 0, stream>>>(Aq, Bq, bias, isc, wsc, out, M, N, K);
}